// Round 5
// baseline (106.005 us; speedup 1.0000x reference)
//
#include <hip/hip_runtime.h>

#define NQ 12
#define DIM 4096
#define NL 6
#define THREADS 512
#define BATCH 768

// ================= GF(2) 12x12 constexpr machinery =================
// Layout chain: Lam(k): I, T, G^2, G^2 T, G^4, G^4 T, G^6.
// Gate (layer lam, bit p) applied in epoch with layout k has
//   physical mask  MU = Lam_k^{-1} G^lam e_p      (pairs h, h^MU)
//   role functional FV = row p of (G^{-lam} Lam_k) (parity(FV&h)=1 -> "1-side")
// One LDS transit per layer boundary; deferred wave-bit gates become
// reg-mask gates after the transit. All derived at compile time + asserted.
struct M12 { unsigned c[12]; };
constexpr unsigned mapv(const M12& m, unsigned v) {
    unsigned r = 0;
    for (int i = 0; i < 12; ++i) if ((v >> i) & 1) r ^= m.c[i];
    return r;
}
constexpr M12 ident() { M12 m{}; for (int i = 0; i < 12; ++i) m.c[i] = 1u << i; return m; }
constexpr M12 mmul(const M12& a, const M12& b) { M12 r{}; for (int i = 0; i < 12; ++i) r.c[i] = mapv(a, b.c[i]); return r; }
constexpr M12 Gmat()  { M12 m{}; for (int i = 0; i < 12; ++i) m.c[i] = (1u << i) | (i ? (1u << (i - 1)) : 0u); return m; }
constexpr M12 Gimat() { M12 m{}; for (int i = 0; i < 12; ++i) m.c[i] = (2u << i) - 1u; return m; }   // ungray columns
constexpr M12 Tmat()  { M12 m = ident(); for (int i = 0; i < 3; ++i) { m.c[i] = 1u << (9 + i); m.c[9 + i] = 1u << i; } return m; }
constexpr M12 Gpow(int n)  { M12 r = ident(); for (int i = 0; i < n; ++i) r = mmul(Gmat(),  r); return r; }
constexpr M12 Gipow(int n) { M12 r = ident(); for (int i = 0; i < n; ++i) r = mmul(Gimat(), r); return r; }
constexpr M12 Lam(int k)    { return (k & 1) ? mmul(Gpow(k - 1), Tmat()) : Gpow(k); }
constexpr M12 LamInv(int k) { return (k & 1) ? mmul(Tmat(), Gipow(k - 1)) : Gipow(k); }
constexpr int par(unsigned v) { int c = 0; for (int b = 0; b < 12; ++b) c ^= (v >> b) & 1; return c; }
constexpr unsigned mask_of(int lam, int p, int k) { return mapv(LamInv(k), mapv(Gpow(lam), 1u << p)); }
constexpr unsigned role_of(int lam, int p, int k) {
    unsigned f = 0;
    for (int b = 0; b < 12; ++b)
        if ((mapv(Gipow(lam), mapv(Lam(k), 1u << b)) >> p) & 1) f |= 1u << b;
    return f;
}
// LDS cell placement: cell(h) = ((h&7)<<9)|(h>>3)  (write = (j<<9)|tid, lane-contiguous)
constexpr unsigned kap(unsigned h) { return ((h & 7u) << 9) | (h >> 3); }
struct Off8  { unsigned v[8]; };
struct Col12 { unsigned v[12]; };
constexpr Off8 offs_of(int k) {           // per-j read offsets for transit k
    M12 R = mmul(LamInv(k - 1), Lam(k));
    Off8 o{};
    for (unsigned j = 0; j < 8; ++j) o.v[j] = kap(mapv(R, j));
    return o;
}
constexpr Col12 cols_of(int k) {          // columns for runtime tid-part of read base
    M12 R = mmul(LamInv(k - 1), Lam(k));
    Col12 c{};
    for (int i = 0; i < 12; ++i) c.v[i] = kap(mapv(R, 1u << i));
    return c;
}

// ================= device helpers =================
__device__ __forceinline__ float2 crow(float2 c0, float2 a, float2 c1, float2 b) {
    float2 r;
    r.x = c0.x * a.x - c0.y * a.y + c1.x * b.x - c1.y * b.y;
    r.y = c0.x * a.y + c0.y * a.x + c1.x * b.y + c1.y * b.x;
    return r;
}
template<int CTRL> __device__ __forceinline__ float dppf(float v) {
    return __int_as_float(__builtin_amdgcn_update_dpp(0, __float_as_int(v), CTRL, 0xF, 0xF, true));
}
template<int XM> __device__ __forceinline__ float bxf(float v) {
    if constexpr (XM == 1)      return dppf<0xB1>(v);   // quad_perm [1,0,3,2]
    else if constexpr (XM == 2) return dppf<0x4E>(v);   // quad_perm [2,3,0,1]
    else if constexpr (XM == 3) return dppf<0x1B>(v);   // quad_perm [3,2,1,0]
    else if constexpr (XM < 32) return __int_as_float(__builtin_amdgcn_ds_swizzle(__float_as_int(v), (XM << 10) | 0x1F));
    else                        return __shfl_xor(v, XM, 64);
}
template<int XM> __device__ __forceinline__ float2 bx2(float2 v) { return make_float2(bxf<XM>(v.x), bxf<XM>(v.y)); }

// ================= one gate pass =================
template<int LAM, int P, int K>
__device__ __forceinline__ void pass(float2 (&amp)[8], const float* __restrict__ gw, const int lane) {
    constexpr unsigned MU = mask_of(LAM, P, K);
    constexpr unsigned FV = role_of(LAM, P, K);
    static_assert(MU != 0 && (MU >> 9) == 0, "mask touches wave bits");
    static_assert((FV >> 9) == 0, "role touches wave bits");
    static_assert(par(MU & FV) == 1, "pair not split by role");
    constexpr int MJ = MU & 7, ML = (int)(MU >> 3);
    constexpr int FJ = FV & 7, FL = (int)(FV >> 3);
    constexpr int GI = (LAM * NQ + (11 - P)) * 8;
    // uniform loads -> SGPRs
    const float2 g00 = make_float2(gw[GI + 0], gw[GI + 1]);
    const float2 g01 = make_float2(gw[GI + 2], gw[GI + 3]);
    const float2 g10 = make_float2(gw[GI + 4], gw[GI + 5]);
    const float2 g11 = make_float2(gw[GI + 6], gw[GI + 7]);
    if constexpr (ML == 0) {
        float2 Oda = g00, Ooa = g01, Odb = g11, Oob = g10;
        if constexpr (FL != 0) {
            const bool lf = (__popc(lane & FL) & 1) != 0;
            Oda = lf ? g11 : g00; Ooa = lf ? g10 : g01;
            Odb = lf ? g00 : g11; Oob = lf ? g01 : g10;
        }
        #pragma unroll
        for (int j = 0; j < 8; ++j) {
            if ((__builtin_popcount((unsigned)(FJ & j)) & 1) == 0) {
                const int jb = j ^ MJ;
                const float2 a = amp[j], b = amp[jb];
                amp[j]  = crow(Oda, a, Ooa, b);
                amp[jb] = crow(Odb, b, Oob, a);
            }
        }
    } else {
        float2 pv[8];
        #pragma unroll
        for (int j = 0; j < 8; ++j) pv[j] = bx2<ML>(amp[j ^ MJ]);
        if constexpr (FL == 0) {
            #pragma unroll
            for (int j = 0; j < 8; ++j) {
                constexpr_bool_hack:;
                const bool r = (__builtin_popcount((unsigned)(FJ & j)) & 1) != 0;  // folds per unrolled j
                amp[j] = crow(r ? g11 : g00, amp[j], r ? g10 : g01, pv[j]);
            }
        } else {
            const bool lf = (__popc(lane & FL) & 1) != 0;
            const float2 O0d = lf ? g11 : g00, O0o = lf ? g10 : g01;
            const float2 O1d = lf ? g00 : g11, O1o = lf ? g01 : g10;
            #pragma unroll
            for (int j = 0; j < 8; ++j) {
                const bool r = (__builtin_popcount((unsigned)(FJ & j)) & 1) != 0;
                amp[j] = crow(r ? O1d : O0d, amp[j], r ? O1o : O0o, pv[j]);
            }
        }
    }
}

// ================= transit (one LDS relayout) =================
template<int K>
__device__ __forceinline__ unsigned tbase(const int tid) {
    constexpr Col12 C = cols_of(K);
    unsigned r = 0;
    #pragma unroll
    for (int i = 3; i < 12; ++i)
        if ((tid >> (i - 3)) & 1) r ^= C.v[i];
    return r;
}
template<int K>
__device__ __forceinline__ void transit(float2 (&amp)[8], float2* __restrict__ st,
                                        const int tid, const unsigned baseT, const unsigned baseG) {
    if constexpr (K > 1) __syncthreads();          // WAR vs previous transit's reads
    #pragma unroll
    for (int j = 0; j < 8; ++j) st[(j << 9) | tid] = amp[j];
    __syncthreads();
    constexpr Off8 OF = offs_of(K);
    const unsigned base = (K & 1) ? baseT : baseG;
    #pragma unroll
    for (int j = 0; j < 8; ++j) amp[j] = st[base ^ OF.v[j]];
}

// ================= readout butterfly stage =================
template<int B>
__device__ __forceinline__ void rstage(float& v, float (&D)[6], float& a9, float& a10, float& a11) {
    constexpr int XM = 1 << B;
    const float sv = bxf<XM>(v);
    D[B] = v - sv;
    v += sv;
    #pragma unroll
    for (int c = 0; c < B; ++c) D[c] += bxf<XM>(D[c]);
    a9 += bxf<XM>(a9); a10 += bxf<XM>(a10); a11 += bxf<XM>(a11);
}

// ================= setup kernel: gates + embedding trig -> d_ws =================
__global__ void setup_kernel(const float* __restrict__ x, const float* __restrict__ params,
                             float* __restrict__ ws) {
    const int t = blockIdx.x * 256 + threadIdx.x;
    if (t < NL * NQ) {
        const float phi = params[t * 3 + 0], th = params[t * 3 + 1], om = params[t * 3 + 2];
        float ct, stt, ca, sa, cb, sb;
        __sincosf(0.5f * th, &stt, &ct);
        __sincosf(0.5f * (phi + om), &sa, &ca);
        __sincosf(0.5f * (phi - om), &sb, &cb);
        float* g = ws + t * 8;
        g[0] =  ca * ct;  g[1] = -sa * ct;    // g00
        g[2] = -cb * stt; g[3] = -sb * stt;   // g01
        g[4] =  cb * stt; g[5] = -sb * stt;   // g10
        g[6] =  ca * ct;  g[7] =  sa * ct;    // g11
    }
    if (t < BATCH * NQ) {
        const int bb = t / NQ, i = t - bb * NQ;
        float s, c;
        __sincosf(0.5f * x[t], &s, &c);
        ws[1024 + bb * 32 + i]      = c;
        ws[1024 + bb * 32 + 16 + i] = s;
    }
}

// ================= main kernel =================
__global__ __launch_bounds__(THREADS, 6)
void qsim_kernel(const float* __restrict__ ws, float* __restrict__ out) {
    __shared__ float2 st[DIM];        // 32 KB transit buffer
    __shared__ float red[8 * 10];
    __shared__ float ev[NQ];

    const int b = blockIdx.x;
    const int tid = threadIdx.x;
    const int lane = tid & 63;
    const int wave = tid >> 6;
    const float* __restrict__ gw = ws;                       // 576 floats (uniform)
    const float* __restrict__ cs = ws + 1024 + b * 32;       // cv[12]@0, sv[12]@16

    const unsigned baseT = tbase<1>(tid);
    const unsigned baseG = tbase<2>(tid);

    // ---- init, layout Lam0 = I: logical = h; qubit i <-> h bit 11-i
    float rt = 1.0f;
    #pragma unroll
    for (int i = 0; i < 9; ++i) {
        const bool bit = (tid >> (8 - i)) & 1;
        rt *= bit ? cs[16 + i] : cs[i];
    }
    const int pt = __popc((unsigned)tid & 0x1FFu);
    float2 amp[8];
    #pragma unroll
    for (int j = 0; j < 8; ++j) {
        float v = rt;
        v *= (j & 4) ? cs[16 + 9]  : cs[9];
        v *= (j & 2) ? cs[16 + 10] : cs[10];
        v *= (j & 1) ? cs[16 + 11] : cs[11];
        const int ph = (pt + __builtin_popcount((unsigned)j)) & 3;
        amp[j].x = (ph == 0) ? v : (ph == 2) ? -v : 0.0f;
        amp[j].y = (ph == 1) ? -v : (ph == 3) ? v : 0.0f;
    }

    // ---- E0 (Lam=I): layer 0, p=0..8
    pass<0,0,0>(amp, gw, lane); pass<0,1,0>(amp, gw, lane); pass<0,2,0>(amp, gw, lane);
    pass<0,3,0>(amp, gw, lane); pass<0,4,0>(amp, gw, lane); pass<0,5,0>(amp, gw, lane);
    pass<0,6,0>(amp, gw, lane); pass<0,7,0>(amp, gw, lane); pass<0,8,0>(amp, gw, lane);
    transit<1>(amp, st, tid, baseT, baseG);
    // ---- E1 (Lam=T): layer 0 p=9..11 (deferred), layer 1 p=4..11
    pass<0,9,1>(amp, gw, lane); pass<0,10,1>(amp, gw, lane); pass<0,11,1>(amp, gw, lane);
    pass<1,11,1>(amp, gw, lane); pass<1,10,1>(amp, gw, lane); pass<1,9,1>(amp, gw, lane);
    pass<1,8,1>(amp, gw, lane);  pass<1,7,1>(amp, gw, lane);  pass<1,6,1>(amp, gw, lane);
    pass<1,5,1>(amp, gw, lane);  pass<1,4,1>(amp, gw, lane);
    transit<2>(amp, st, tid, baseT, baseG);
    // ---- E2 (Lam=G^2): layer 1 p=0..3 (deferred), layer 2 p=0..8
    pass<1,0,2>(amp, gw, lane); pass<1,1,2>(amp, gw, lane); pass<1,2,2>(amp, gw, lane); pass<1,3,2>(amp, gw, lane);
    pass<2,0,2>(amp, gw, lane); pass<2,1,2>(amp, gw, lane); pass<2,2,2>(amp, gw, lane);
    pass<2,3,2>(amp, gw, lane); pass<2,4,2>(amp, gw, lane); pass<2,5,2>(amp, gw, lane);
    pass<2,6,2>(amp, gw, lane); pass<2,7,2>(amp, gw, lane); pass<2,8,2>(amp, gw, lane);
    transit<3>(amp, st, tid, baseT, baseG);
    // ---- E3 (Lam=G^2 T)
    pass<2,9,3>(amp, gw, lane); pass<2,10,3>(amp, gw, lane); pass<2,11,3>(amp, gw, lane);
    pass<3,11,3>(amp, gw, lane); pass<3,10,3>(amp, gw, lane); pass<3,9,3>(amp, gw, lane);
    pass<3,8,3>(amp, gw, lane);  pass<3,7,3>(amp, gw, lane);  pass<3,6,3>(amp, gw, lane);
    pass<3,5,3>(amp, gw, lane);  pass<3,4,3>(amp, gw, lane);
    transit<4>(amp, st, tid, baseT, baseG);
    // ---- E4 (Lam=G^4)
    pass<3,0,4>(amp, gw, lane); pass<3,1,4>(amp, gw, lane); pass<3,2,4>(amp, gw, lane); pass<3,3,4>(amp, gw, lane);
    pass<4,0,4>(amp, gw, lane); pass<4,1,4>(amp, gw, lane); pass<4,2,4>(amp, gw, lane);
    pass<4,3,4>(amp, gw, lane); pass<4,4,4>(amp, gw, lane); pass<4,5,4>(amp, gw, lane);
    pass<4,6,4>(amp, gw, lane); pass<4,7,4>(amp, gw, lane); pass<4,8,4>(amp, gw, lane);
    transit<5>(amp, st, tid, baseT, baseG);
    // ---- E5 (Lam=G^4 T)
    pass<4,9,5>(amp, gw, lane); pass<4,10,5>(amp, gw, lane); pass<4,11,5>(amp, gw, lane);
    pass<5,11,5>(amp, gw, lane); pass<5,10,5>(amp, gw, lane); pass<5,9,5>(amp, gw, lane);
    pass<5,8,5>(amp, gw, lane);  pass<5,7,5>(amp, gw, lane);  pass<5,6,5>(amp, gw, lane);
    pass<5,5,5>(amp, gw, lane);  pass<5,4,5>(amp, gw, lane);
    transit<6>(amp, st, tid, baseT, baseG);
    // ---- E6 (Lam=G^6): layer 5 p=0..3
    pass<5,0,6>(amp, gw, lane); pass<5,1,6>(amp, gw, lane); pass<5,2,6>(amp, gw, lane); pass<5,3,6>(amp, gw, lane);

    // ---- readout: layout G^6 -> sign(qubit q) = h bit (11-q)
    float p8[8];
    #pragma unroll
    for (int j = 0; j < 8; ++j) p8[j] = amp[j].x * amp[j].x + amp[j].y * amp[j].y;
    const float t01 = p8[0] + p8[1], d01 = p8[0] - p8[1];
    const float t23 = p8[2] + p8[3], d23 = p8[2] - p8[3];
    const float t45 = p8[4] + p8[5], d45 = p8[4] - p8[5];
    const float t67 = p8[6] + p8[7], d67 = p8[6] - p8[7];
    const float s03 = t01 + t23, s47 = t45 + t67;
    float S   = s03 + s47;                       // DC; wave-bit qubits 0..2
    float a11 = (d01 + d23) + (d45 + d67);       // sign j0 -> qubit 11
    float a10 = (t01 - t23) + (t45 - t67);       // sign j1 -> qubit 10
    float a9  = s03 - s47;                       // sign j2 -> qubit 9
    float D[6];
    rstage<0>(S, D, a9, a10, a11); rstage<1>(S, D, a9, a10, a11);
    rstage<2>(S, D, a9, a10, a11); rstage<3>(S, D, a9, a10, a11);
    rstage<4>(S, D, a9, a10, a11); rstage<5>(S, D, a9, a10, a11);
    if (lane == 0) {
        float* rw = red + wave * 10;
        rw[0] = S;
        #pragma unroll
        for (int c = 0; c < 6; ++c) rw[1 + c] = D[c];   // D[b]: lane bit b -> qubit 8-b
        rw[7] = a9; rw[8] = a10; rw[9] = a11;
    }
    __syncthreads();
    if (tid < NQ) {
        float e = 0.0f;
        #pragma unroll
        for (int w = 0; w < 8; ++w) {
            const float* rw = red + w * 10;
            float s;
            if (tid == 0)      s = ((w >> 2) & 1) ? -rw[0] : rw[0];   // qubit0 <-> h11 = wave bit2
            else if (tid == 1) s = ((w >> 1) & 1) ? -rw[0] : rw[0];
            else if (tid == 2) s = ((w >> 0) & 1) ? -rw[0] : rw[0];
            else if (tid < 9)  s = rw[1 + (8 - tid)];                 // qubit q <-> lane bit (8-q)
            else               s = rw[7 + (tid - 9)];
            e += s;
        }
        ev[tid] = e;
    }
    __syncthreads();
    if (tid < NQ) {
        float Sm = 0.0f;
        #pragma unroll
        for (int i = 0; i < NQ; ++i) Sm += ev[i];
        out[b * NQ + tid] = (Sm + 12.0f) * (1.0f / 11.0f) - ev[tid] - 2.0f;
    }
}

extern "C" void kernel_launch(void* const* d_in, const int* in_sizes, int n_in,
                              void* d_out, int out_size, void* d_ws, size_t ws_size,
                              hipStream_t stream) {
    const float* x      = (const float*)d_in[0];
    const float* params = (const float*)d_in[1];
    float* ws  = (float*)d_ws;
    float* out = (float*)d_out;
    setup_kernel<<<dim3(36), dim3(256), 0, stream>>>(x, params, ws);
    qsim_kernel<<<dim3(BATCH), dim3(THREADS), 0, stream>>>(ws, out);
}

// Round 8
// 96.259 us; speedup vs baseline: 1.1012x; 1.1012x over previous
//
#include <hip/hip_runtime.h>

#define NQ 12
#define DIM 4096
#define NL 6
#define THREADS 256
#define BATCH 768

// ================= GF(2) 12x12 constexpr machinery =================
// We simulate the circuit with the CNOT chain folded as the index map
// G(v)=v^(v>>1). Storage: logical index m = Lam_k * h, h = (tid<<4)|j.
// Epoch layouts: Lam(2L) = G^L*S (gates p=6..11 of layer L -> h bits 0..5),
//                Lam(2L+1) = G^L (gates p=0..5 -> h bits 0..5),
//                Lam(12) = G^6 (readout: sign(q) = h bit (11-q)).
// Transits R = Lam_old^-1 Lam_new: odd->S, even->G*S, final->G.
// All matrices memoized as separate constexpr globals (constexpr step limit!).
struct M12 { unsigned c[12]; };
constexpr unsigned mapv(const M12& m, unsigned v) {
    unsigned r = 0;
    for (int i = 0; i < 12; ++i) if ((v >> i) & 1) r ^= m.c[i];
    return r;
}
constexpr M12 ident() { M12 m{}; for (int i = 0; i < 12; ++i) m.c[i] = 1u << i; return m; }
constexpr M12 mmul(const M12& a, const M12& b) { M12 r{}; for (int i = 0; i < 12; ++i) r.c[i] = mapv(a, b.c[i]); return r; }
constexpr M12 Gmat()  { M12 m{}; for (int i = 0; i < 12; ++i) m.c[i] = (1u << i) | (i ? (1u << (i - 1)) : 0u); return m; }
constexpr M12 Gimat() { M12 m{}; for (int i = 0; i < 12; ++i) m.c[i] = (2u << i) - 1u; return m; }   // ungray columns
constexpr M12 Smat()  { M12 m{}; for (int i = 0; i < 12; ++i) m.c[i] = (i < 6) ? (1u << (i + 6)) : (1u << (i - 6)); return m; }
struct Pow7 { M12 p[7]; };
constexpr Pow7 mkpow(const M12 g) { Pow7 t{}; t.p[0] = ident(); for (int i = 1; i < 7; ++i) t.p[i] = mmul(g, t.p[i - 1]); return t; }
constexpr Pow7 GP  = mkpow(Gmat());    // G^0..G^6
constexpr Pow7 GIP = mkpow(Gimat());   // G^0..G^-6
struct LamT { M12 l[13]; };
constexpr LamT mklam() {
    LamT t{};
    for (int k = 0; k < 12; ++k) t.l[k] = (k & 1) ? GP.p[k >> 1] : mmul(GP.p[k >> 1], Smat());
    t.l[12] = GP.p[6];
    return t;
}
constexpr LamT mklami() {
    LamT t{};
    for (int k = 0; k < 12; ++k) t.l[k] = (k & 1) ? GIP.p[k >> 1] : mmul(Smat(), GIP.p[k >> 1]);
    t.l[12] = GIP.p[6];
    return t;
}
constexpr LamT LAMT  = mklam();
constexpr LamT LAMIT = mklami();
constexpr bool eqm(const M12& a, const M12& b) { for (int i = 0; i < 12; ++i) if (a.c[i] != b.c[i]) return false; return true; }
constexpr unsigned mask_of(int lam, int p, int k) { return mapv(LAMIT.l[k], mapv(GP.p[lam], 1u << p)); }
constexpr unsigned role_of(int lam, int p, int k) {
    unsigned f = 0;
    for (int b = 0; b < 12; ++b)
        if ((mapv(GIP.p[lam], mapv(LAMT.l[k], 1u << b)) >> p) & 1) f |= 1u << b;
    return f;
}
constexpr bool check_layer(int L) {
    for (int p = 0; p < 12; ++p) {
        const int k = (p >= 6) ? 2 * L : 2 * L + 1;
        const unsigned exp_ = (p >= 6) ? (1u << (p - 6)) : (1u << p);
        if (mask_of(L, p, k) != exp_) return false;
        if (role_of(L, p, k) != exp_) return false;
    }
    return true;
}
static_assert(check_layer(0), "layer0 masks/roles not unit cheap bits");
static_assert(check_layer(1), "layer1");
static_assert(check_layer(2), "layer2");
static_assert(check_layer(3), "layer3");
static_assert(check_layer(4), "layer4");
static_assert(check_layer(5), "layer5");
constexpr M12 Rk(int k) { return mmul(LAMIT.l[k - 1], LAMT.l[k]); }
constexpr M12 R_S  = Smat();
constexpr M12 R_GS = mmul(Gmat(), Smat());
constexpr M12 R_G  = Gmat();
static_assert(eqm(Rk(1), R_S) && eqm(Rk(3), R_S) && eqm(Rk(11), R_S), "T1 != S");
static_assert(eqm(Rk(2), R_GS) && eqm(Rk(10), R_GS), "T2 != G*S");
static_assert(eqm(Rk(12), R_G), "T3 != G");

// LDS cell map: cell(h)=((h&15)<<8)|(h>>4), then linear XOR-swizzle for banks.
constexpr unsigned kap(unsigned h) {
    const unsigned cell = ((h & 15u) << 8) | (h >> 4);
    return cell ^ ((cell >> 8) & 15u) ^ (((cell >> 6) & 3u) << 4);
}
struct Off16 { unsigned v[16]; };
struct Col8  { unsigned v[8]; };
constexpr Off16 roff(const M12& R) { Off16 o{}; for (unsigned j = 0; j < 16; ++j) o.v[j] = kap(mapv(R, j)); return o; }
constexpr Col8  rcol(const M12& R) { Col8 c{}; for (int i = 0; i < 8; ++i) c.v[i] = kap(mapv(R, 1u << (4 + i))); return c; }
constexpr Off16 OFF_S = roff(R_S), OFF_GS = roff(R_GS), OFF_G = roff(R_G);
constexpr Col8  COL_S = rcol(R_S), COL_GS = rcol(R_GS), COL_G = rcol(R_G);

// ================= packed-FP32 complex helpers (double = {re=lo, im=hi}) ====
// r = c*a:  lo = c.re*a.re - c.im*a.im ; hi = c.re*a.im + c.im*a.re
__device__ __forceinline__ double pkmul_s(double c, double a) {
    double r;
    asm("v_pk_mul_f32 %0, %1, %2 op_sel:[0,0] op_sel_hi:[0,1]\n\t"
        "v_pk_fma_f32 %0, %1, %2, %0 op_sel:[1,1,0] op_sel_hi:[1,0,1] neg_lo:[1,0,0]"
        : "=&v"(r) : "s"(c), "v"(a));
    return r;
}
__device__ __forceinline__ double pkfma_s(double c, double a, double d) {
    double r;
    asm("v_pk_fma_f32 %0, %1, %2, %3 op_sel:[0,0,0] op_sel_hi:[0,1,1]\n\t"
        "v_pk_fma_f32 %0, %1, %2, %0 op_sel:[1,1,0] op_sel_hi:[1,0,1] neg_lo:[1,0,0]"
        : "=&v"(r) : "s"(c), "v"(a), "v"(d));
    return r;
}
__device__ __forceinline__ double pkmul_v(double c, double a) {
    double r;
    asm("v_pk_mul_f32 %0, %1, %2 op_sel:[0,0] op_sel_hi:[0,1]\n\t"
        "v_pk_fma_f32 %0, %1, %2, %0 op_sel:[1,1,0] op_sel_hi:[1,0,1] neg_lo:[1,0,0]"
        : "=&v"(r) : "v"(c), "v"(a));
    return r;
}
__device__ __forceinline__ double pkfma_v(double c, double a, double d) {
    double r;
    asm("v_pk_fma_f32 %0, %1, %2, %3 op_sel:[0,0,0] op_sel_hi:[0,1,1]\n\t"
        "v_pk_fma_f32 %0, %1, %2, %0 op_sel:[1,1,0] op_sel_hi:[1,0,1] neg_lo:[1,0,0]"
        : "=&v"(r) : "v"(c), "v"(a), "v"(d));
    return r;
}

template<int CTRL>
__device__ __forceinline__ double dpp64(double v) {
    const int lo = __builtin_amdgcn_update_dpp(0, __double2loint(v), CTRL, 0xF, 0xF, true);
    const int hi = __builtin_amdgcn_update_dpp(0, __double2hiint(v), CTRL, 0xF, 0xF, true);
    return __hiloint2double(hi, lo);
}
template<int CTRL> __device__ __forceinline__ float dppf(float v) {
    return __int_as_float(__builtin_amdgcn_update_dpp(0, __float_as_int(v), CTRL, 0xF, 0xF, true));
}
template<int XM> __device__ __forceinline__ float bxf(float v) {
    if constexpr (XM == 1)      return dppf<0xB1>(v);
    else if constexpr (XM == 2) return dppf<0x4E>(v);
    else if constexpr (XM < 32) return __int_as_float(__builtin_amdgcn_ds_swizzle(__float_as_int(v), (XM << 10) | 0x1F));
    else                        return __shfl_xor(v, XM, 64);
}

// ================= gate passes =================
// reg gate on j-bit RB: 0-side = bit clear; rows: (g00,g01) / (g10,g11)
template<int RB>
__device__ __forceinline__ void regpassPK(double (&amp)[16], const double* __restrict__ g) {
    const double g00 = g[0], g01 = g[1], g10 = g[2], g11 = g[3];
    #pragma unroll
    for (int j = 0; j < 16; ++j)
        if (!(j & (1 << RB))) {
            const int jb = j | (1 << RB);
            const double a = amp[j], b2 = amp[jb];
            amp[j]  = pkfma_s(g01, b2, pkmul_s(g00, a));
            amp[jb] = pkfma_s(g10, a,  pkmul_s(g11, b2));
        }
}
// DPP gate on lane bit (XM = 1 or 2): side selects gate row
template<int XM>
__device__ __forceinline__ void dpppassPK(double (&amp)[16], const double* __restrict__ g, const int lane) {
    constexpr int CTRL = (XM == 1) ? 0xB1 : 0x4E;
    const bool side = (lane & XM) != 0;
    const double cA = side ? g[3] : g[0];   // own coeff
    const double cB = side ? g[2] : g[1];   // recv coeff
    #pragma unroll
    for (int j = 0; j < 16; ++j) {
        const double r = dpp64<CTRL>(amp[j]);
        amp[j] = pkfma_v(cB, r, pkmul_v(cA, amp[j]));
    }
}

template<int L>
__device__ __forceinline__ void epochA(double (&amp)[16], const double* __restrict__ gd, const int lane) {
    const double* gL = gd + L * 48;   // 12 gates x 4 doubles; qubit q at gL + 4q
    regpassPK<0>(amp, gL + 5 * 4);    // p=6  -> j0
    regpassPK<1>(amp, gL + 4 * 4);    // p=7  -> j1
    regpassPK<2>(amp, gL + 3 * 4);    // p=8  -> j2
    regpassPK<3>(amp, gL + 2 * 4);    // p=9  -> j3
    dpppassPK<1>(amp, gL + 1 * 4, lane);  // p=10 -> lane0
    dpppassPK<2>(amp, gL + 0 * 4, lane);  // p=11 -> lane1
}
template<int L>
__device__ __forceinline__ void epochB(double (&amp)[16], const double* __restrict__ gd, const int lane) {
    const double* gL = gd + L * 48;
    regpassPK<0>(amp, gL + 11 * 4);   // p=0 -> j0
    regpassPK<1>(amp, gL + 10 * 4);   // p=1 -> j1
    regpassPK<2>(amp, gL +  9 * 4);   // p=2 -> j2
    regpassPK<3>(amp, gL +  8 * 4);   // p=3 -> j3
    dpppassPK<1>(amp, gL + 7 * 4, lane);  // p=4 -> lane0
    dpppassPK<2>(amp, gL + 6 * 4, lane);  // p=5 -> lane1
}

// ================= transit =================
template<int RSEL, bool FIRST>
__device__ __forceinline__ void transit(double (&amp)[16], double* __restrict__ st,
                                        const unsigned wbase, const unsigned rbase) {
    if constexpr (!FIRST) __syncthreads();
    #pragma unroll
    for (int j = 0; j < 16; ++j)
        st[wbase ^ (unsigned)((j << 8) ^ j)] = amp[j];
    __syncthreads();
    constexpr Off16 OF = (RSEL == 0) ? OFF_S : (RSEL == 1) ? OFF_GS : OFF_G;
    #pragma unroll
    for (int j = 0; j < 16; ++j) amp[j] = st[rbase ^ OF.v[j]];
}
template<int RSEL>
__device__ __forceinline__ unsigned rbase_of(const int tid) {
    constexpr Col8 C = (RSEL == 0) ? COL_S : (RSEL == 1) ? COL_GS : COL_G;
    unsigned r = 0;
    #pragma unroll
    for (int i = 0; i < 8; ++i) if ((tid >> i) & 1) r ^= C.v[i];
    return r;
}

// ================= readout butterfly stage =================
template<int B>
__device__ __forceinline__ void rstage(float& S, float (&D)[6], float (&Bv)[4]) {
    constexpr int XM = 1 << B;
    const float sv = bxf<XM>(S);
    D[B] = S - sv;
    S += sv;
    #pragma unroll
    for (int c = 0; c < B; ++c) D[c] += bxf<XM>(D[c]);
    #pragma unroll
    for (int q = 0; q < 4; ++q) Bv[q] += bxf<XM>(Bv[q]);
}

// ================= setup: gates + embedding trig -> d_ws =================
__global__ void setup_kernel(const float* __restrict__ x, const float* __restrict__ params,
                             float* __restrict__ ws) {
    const int t = blockIdx.x * 256 + threadIdx.x;
    if (t < NL * NQ) {
        const float phi = params[t * 3 + 0], th = params[t * 3 + 1], om = params[t * 3 + 2];
        float ct, stt, ca, sa, cb, sb;
        __sincosf(0.5f * th, &stt, &ct);
        __sincosf(0.5f * (phi + om), &sa, &ca);
        __sincosf(0.5f * (phi - om), &sb, &cb);
        float* g = ws + t * 8;
        g[0] =  ca * ct;  g[1] = -sa * ct;    // g00
        g[2] = -cb * stt; g[3] = -sb * stt;   // g01
        g[4] =  cb * stt; g[5] = -sb * stt;   // g10
        g[6] =  ca * ct;  g[7] =  sa * ct;    // g11
    }
    if (t < BATCH * NQ) {
        const int bb = t / NQ, i = t - bb * NQ;
        float s, c;
        __sincosf(0.5f * x[t], &s, &c);
        ws[1024 + bb * 32 + i]      = c;
        ws[1024 + bb * 32 + 16 + i] = s;
    }
}

// ================= main kernel =================
__global__ __launch_bounds__(THREADS, 4)
void qsim_kernel(const float* __restrict__ ws, float* __restrict__ out) {
    __shared__ double st[DIM];        // 32 KB transit buffer
    __shared__ float red[4 * 11];
    __shared__ float ev[NQ];

    const int b = blockIdx.x;
    const int tid = threadIdx.x;
    const int lane = tid & 63;
    const int wave = tid >> 6;
    const double* __restrict__ gd = (const double*)ws;        // 72 gates x 4 doubles
    const float*  __restrict__ cs = ws + 1024 + b * 32;       // cv[12]@0, sv[12]@16

    const unsigned wbase = (unsigned)tid ^ (((unsigned)tid & 0xC0u) >> 2);
    const unsigned rbS  = rbase_of<0>(tid);
    const unsigned rbGS = rbase_of<1>(tid);
    const unsigned rbG  = rbase_of<2>(tid);

    // ---- init in layout Lam0 = S
    float rt = 1.0f;
    rt *= ((tid >> 1) & 1) ? cs[16 + 0]  : cs[0];
    rt *= ((tid >> 0) & 1) ? cs[16 + 1]  : cs[1];
    rt *= ((tid >> 7) & 1) ? cs[16 + 6]  : cs[6];
    rt *= ((tid >> 6) & 1) ? cs[16 + 7]  : cs[7];
    rt *= ((tid >> 5) & 1) ? cs[16 + 8]  : cs[8];
    rt *= ((tid >> 4) & 1) ? cs[16 + 9]  : cs[9];
    rt *= ((tid >> 3) & 1) ? cs[16 + 10] : cs[10];
    rt *= ((tid >> 2) & 1) ? cs[16 + 11] : cs[11];
    const int pt = __popc((unsigned)tid & 0xFFu);

    double amp[16];
    #pragma unroll
    for (int j = 0; j < 16; ++j) {
        float v = rt;
        v *= (j & 8) ? cs[16 + 2] : cs[2];
        v *= (j & 4) ? cs[16 + 3] : cs[3];
        v *= (j & 2) ? cs[16 + 4] : cs[4];
        v *= (j & 1) ? cs[16 + 5] : cs[5];
        const int ph = (pt + __builtin_popcount((unsigned)j)) & 3;
        const float re = (ph == 0) ? v : (ph == 2) ? -v : 0.0f;
        const float im = (ph == 1) ? -v : (ph == 3) ? v : 0.0f;
        amp[j] = __hiloint2double(__float_as_int(im), __float_as_int(re));
    }

    // ---- 6 layers: epochA (p6-11), T1=S, epochB (p0-5), T2=G*S (last: T3=G)
    epochA<0>(amp, gd, lane); transit<0, true >(amp, st, wbase, rbS);
    epochB<0>(amp, gd, lane); transit<1, false>(amp, st, wbase, rbGS);
    epochA<1>(amp, gd, lane); transit<0, false>(amp, st, wbase, rbS);
    epochB<1>(amp, gd, lane); transit<1, false>(amp, st, wbase, rbGS);
    epochA<2>(amp, gd, lane); transit<0, false>(amp, st, wbase, rbS);
    epochB<2>(amp, gd, lane); transit<1, false>(amp, st, wbase, rbGS);
    epochA<3>(amp, gd, lane); transit<0, false>(amp, st, wbase, rbS);
    epochB<3>(amp, gd, lane); transit<1, false>(amp, st, wbase, rbGS);
    epochA<4>(amp, gd, lane); transit<0, false>(amp, st, wbase, rbS);
    epochB<4>(amp, gd, lane); transit<1, false>(amp, st, wbase, rbGS);
    epochA<5>(amp, gd, lane); transit<0, false>(amp, st, wbase, rbS);
    epochB<5>(amp, gd, lane); transit<2, false>(amp, st, wbase, rbG);   // -> Lam = G^6

    // ---- readout: sign(q) = h bit (11-q); j0..3 -> q11..8, lane0..5 -> q7..2, wave0,1 -> q1,0
    float p16[16];
    #pragma unroll
    for (int j = 0; j < 16; ++j) {
        const float re = __int_as_float(__double2loint(amp[j]));
        const float im = __int_as_float(__double2hiint(amp[j]));
        p16[j] = re * re + im * im;
    }
    float e8[8], B0 = 0.0f;
    #pragma unroll
    for (int i = 0; i < 8; ++i) { e8[i] = p16[2*i] + p16[2*i+1]; B0 += p16[2*i] - p16[2*i+1]; }
    float f4[4], B1 = 0.0f;
    #pragma unroll
    for (int i = 0; i < 4; ++i) { f4[i] = e8[2*i] + e8[2*i+1]; B1 += e8[2*i] - e8[2*i+1]; }
    const float h0 = f4[0] + f4[1], h1 = f4[2] + f4[3];
    const float B2 = (f4[0] - f4[1]) + (f4[2] - f4[3]);
    float S = h0 + h1;
    float Bv[4] = { B0, B1, B2, h0 - h1 };   // Bv[b] -> qubit 11-b
    float D[6];
    rstage<0>(S, D, Bv); rstage<1>(S, D, Bv); rstage<2>(S, D, Bv);
    rstage<3>(S, D, Bv); rstage<4>(S, D, Bv); rstage<5>(S, D, Bv);
    if (lane == 0) {
        float* rw = red + wave * 11;
        rw[0] = S;
        #pragma unroll
        for (int c = 0; c < 6; ++c) rw[1 + c] = D[c];   // D[b] -> qubit 7-b
        #pragma unroll
        for (int q = 0; q < 4; ++q) rw[7 + q] = Bv[q];
    }
    __syncthreads();
    if (tid < NQ) {
        float e = 0.0f;
        #pragma unroll
        for (int w = 0; w < 4; ++w) {
            const float* rw = red + w * 11;
            float s;
            if (tid == 0)      s = ((w >> 1) & 1) ? -rw[0] : rw[0];   // qubit0 <-> h11 (wave bit1)
            else if (tid == 1) s = ((w >> 0) & 1) ? -rw[0] : rw[0];   // qubit1 <-> h10 (wave bit0)
            else if (tid < 8)  s = rw[1 + (7 - tid)];                 // qubits 2..7 <-> lane bits 5..0
            else               s = rw[7 + (11 - tid)];                // qubits 8..11 <-> j bits 3..0
            e += s;
        }
        ev[tid] = e;
    }
    __syncthreads();
    if (tid < NQ) {
        float Sm = 0.0f;
        #pragma unroll
        for (int i = 0; i < NQ; ++i) Sm += ev[i];
        out[b * NQ + tid] = (Sm + 12.0f) * (1.0f / 11.0f) - ev[tid] - 2.0f;
    }
}

extern "C" void kernel_launch(void* const* d_in, const int* in_sizes, int n_in,
                              void* d_out, int out_size, void* d_ws, size_t ws_size,
                              hipStream_t stream) {
    const float* x      = (const float*)d_in[0];
    const float* params = (const float*)d_in[1];
    float* ws  = (float*)d_ws;
    float* out = (float*)d_out;
    setup_kernel<<<dim3(36), dim3(256), 0, stream>>>(x, params, ws);
    qsim_kernel<<<dim3(BATCH), dim3(THREADS), 0, stream>>>(ws, out);
}